// Round 5
// baseline (29388.849 us; speedup 1.0000x reference)
//
#include <hip/hip_runtime.h>
#include <hip/hip_bf16.h>

using bf16 = __hip_bfloat16;

// ---------- runtime-dtype input loader: flag==1 -> f32, flag==0 -> bf16 ----------
__device__ __forceinline__ float ldin(const void* p, long i, int f32) {
    return f32 ? ((const float*)p)[i] : __bfloat162float(((const bf16*)p)[i]);
}

// Probe: even-indexed bf16 reads of inp. bf16 data -> sane magnitudes (~100%);
// f32 data -> even bf16 = f32 low-half mantissa garbage (~8% sane). Little-endian.
__global__ void detect_dtype(const void* __restrict__ inp, int* __restrict__ flag)
{
    const int t = threadIdx.x;  // 64
    int sane_cnt = 0;
#pragma unroll
    for (int s = 0; s < 4; s++) {
        float v = __bfloat162float(((const bf16*)inp)[2 * (t + 64 * s)]);
        float a = fabsf(v);
        bool sane = (a == 0.f) || (a > 9e-4f && a < 1000.f);
        unsigned long long m = __ballot(sane);
        sane_cnt += (int)__popcll(m);
    }
    if (t == 0) *flag = (sane_cnt > 128) ? 0 : 1;   // 256 samples; bf16 ~256 sane, f32 ~20
}

// dst[i] = i<nsrc ? scale*src[srcOff+i] : 0   for i<ndst
__global__ __launch_bounds__(256)
void cvt_gen(const void* __restrict__ src, long srcOff, bf16* __restrict__ dst,
             long nsrc, long ndst, const int* __restrict__ flag, float scale)
{
    const int f = *flag;
    for (long i = (long)blockIdx.x * 256 + threadIdx.x; i < ndst; i += (long)gridDim.x * 256)
        dst[i] = __float2bfloat16(i < nsrc ? scale * ldin(src, srcOff + i, f) : 0.f);
}

// ctxB_b[2048][512] = concat(x[b], y[b])
__global__ __launch_bounds__(256)
void cvt_ctx_b(const void* __restrict__ x, const void* __restrict__ y,
               bf16* __restrict__ ctx, long b, const int* __restrict__ flag)
{
    const int f = *flag;
    const long id = (long)blockIdx.x * 256 + threadIdx.x;   // 1,048,576
    if (id >= 2048L * 512) return;
    const long r = id >> 9, c = id & 511;
    float v = (r < 1024) ? ldin(x, (b * 1024 + r) * 512 + c, f)
                         : ldin(y, (b * 1024 + (r - 1024)) * 512 + c, f);
    ctx[id] = __float2bfloat16(v);
}

// WfP[1152][2080]: (r<1027 && c<2051) ? Wf[r*2051+c] : 0
__global__ __launch_bounds__(256)
void cvt_wf(const void* __restrict__ Wf, bf16* __restrict__ WfP, const int* __restrict__ flag)
{
    const int f = *flag;
    const long id = (long)blockIdx.x * 256 + threadIdx.x;   // 2,396,160
    if (id >= 1152L * 2080) return;
    const long r = id / 2080, c = id % 2080;
    float v = (r < 1027 && c < 2051) ? ldin(Wf, r * 2051 + c, f) : 0.f;
    WfP[id] = __float2bfloat16(v);
}

// Kb8[h][2048+r][d] = r<3 ? mkS[h*192+r*64+d] : 0   (r<128)
__global__ __launch_bounds__(256)
void fill_k_tok(const bf16* __restrict__ mkS, bf16* __restrict__ Kb8)
{
    const int id = blockIdx.x * 256 + threadIdx.x;          // 65,536
    const int h = id >> 13, r = (id >> 6) & 127, d = id & 63;
    Kb8[(long)h * 2176 * 64 + (2048 + r) * 64 + d] =
        (r < 3) ? mkS[h * 192 + r * 64 + d] : __float2bfloat16(0.f);
}

// Skb8[h][1024+r][d] = r<3 ? SmkS[h*192+r*64+d] : 0   (r<128)
__global__ __launch_bounds__(256)
void fill_sk_tok(const bf16* __restrict__ SmkS, bf16* __restrict__ Skb8)
{
    const int id = blockIdx.x * 256 + threadIdx.x;          // 65,536
    const int h = id >> 13, r = (id >> 6) & 127, d = id & 63;
    Skb8[(long)h * 1152 * 64 + (1024 + r) * 64 + d] =
        (r < 3) ? SmkS[h * 192 + r * 64 + d] : __float2bfloat16(0.f);
}

// SvT8[h][d][1024+c] = c<3 ? SmvS[h*192+c*64+d] : 0   (c<32)
__global__ __launch_bounds__(256)
void fill_svt_tok(const bf16* __restrict__ SmvS, bf16* __restrict__ SvT8)
{
    const int id = blockIdx.x * 256 + threadIdx.x;          // 16,384
    const int h = id >> 11, d = (id >> 5) & 63, c = id & 31;
    SvT8[(long)h * 64 * 1056 + d * 1056 + 1024 + c] =
        (c < 3) ? SmvS[h * 192 + c * 64 + d] : __float2bfloat16(0.f);
}

// SvT[d][j] = Svbh[j][d]  for j<1024, d<64
__global__ __launch_bounds__(256)
void transpose_sv(const bf16* __restrict__ Svbh, bf16* __restrict__ SvT)
{
    const int id = blockIdx.x * 256 + threadIdx.x;          // 65,536
    const int d = id >> 10, j = id & 1023;
    SvT[(long)d * 1056 + j] = Svbh[(long)j * 64 + d];
}

// ---------------- simple, correctness-first NT GEMM ----------------
// C[m][n] = sum_k A[m][k]*B[n][k] (+bias[n]) (+add[m][n])
// Tiles 64x64, K-tile 16. M mult of 64, K mult of 16. B needs grid.x*64 readable rows.
// Stores: n<validN -> val; validN<=n<zeroN -> 0; else skip.
template<int OUTF32>
__global__ __launch_bounds__(256)
void gemm_nt(const bf16* __restrict__ A, long lda,
             const bf16* __restrict__ B, long ldb,
             void* __restrict__ Cv, long ldc,
             int K,
             const bf16* __restrict__ bias,
             const bf16* __restrict__ add, long ldadd,
             int validN, int zeroN)
{
    __shared__ float As[64][17];
    __shared__ float Bs[64][17];

    const int t  = threadIdx.x;
    const int bn = blockIdx.x, bm = blockIdx.y;
    const int ty = t >> 4, tx = t & 15;

    const bf16* Ab = A + (long)bm * 64 * lda;
    const bf16* Bb = B + (long)bn * 64 * ldb;

    const int lr  = t >> 2;         // 0..63
    const int lk0 = (t & 3) << 2;   // 0,4,8,12

    float acc[4][4];
#pragma unroll
    for (int i = 0; i < 4; i++)
#pragma unroll
        for (int j = 0; j < 4; j++) acc[i][j] = 0.f;

    for (int k0 = 0; k0 < K; k0 += 16) {
        __syncthreads();
#pragma unroll
        for (int u = 0; u < 4; u++) {
            As[lr][lk0 + u] = __bfloat162float(Ab[(long)lr * lda + k0 + lk0 + u]);
            Bs[lr][lk0 + u] = __bfloat162float(Bb[(long)lr * ldb + k0 + lk0 + u]);
        }
        __syncthreads();
#pragma unroll
        for (int kk = 0; kk < 16; kk++) {
            float a[4], b[4];
#pragma unroll
            for (int i = 0; i < 4; i++) a[i] = As[ty * 4 + i][kk];
#pragma unroll
            for (int j = 0; j < 4; j++) b[j] = Bs[tx * 4 + j][kk];
#pragma unroll
            for (int i = 0; i < 4; i++)
#pragma unroll
                for (int j = 0; j < 4; j++) acc[i][j] += a[i] * b[j];
        }
    }

    const int r0 = bm * 64 + ty * 4;
    const int c0 = bn * 64 + tx * 4;
#pragma unroll
    for (int j = 0; j < 4; j++) {
        const int c = c0 + j;
        if (c >= zeroN) continue;
        const bool valid = c < validN;
        float bv = (valid && bias) ? __bfloat162float(bias[c]) : 0.f;
#pragma unroll
        for (int i = 0; i < 4; i++) {
            const long rg = r0 + i;
            if (OUTF32) {
                ((float*)Cv)[rg * ldc + c] = acc[i][j] + bv;
            } else {
                float v = 0.f;
                if (valid) {
                    v = acc[i][j] + bv;
                    if (add) v += __bfloat162float(add[rg * ldadd + c]);
                }
                ((bf16*)Cv)[rg * ldc + c] = __float2bfloat16(v);
            }
        }
    }
}

// row softmax of scale*L over cols [0,V); writes bf16 P, zero-fills cols [V,W)
__global__ __launch_bounds__(256)
void softmax_rows(const float* __restrict__ L, long ldl,
                  bf16* __restrict__ P, long ldp,
                  int V, int W, float scale)
{
    const long row = blockIdx.x;
    const float* lr = L + row * ldl;
    bf16* pr = P + row * ldp;
    const int t = threadIdx.x;
    const int wave = t >> 6, lane = t & 63;
    __shared__ float red[4];

    float m = -3.0e38f;
    for (int c = t; c < V; c += 256) m = fmaxf(m, lr[c]);
#pragma unroll
    for (int o = 32; o > 0; o >>= 1) m = fmaxf(m, __shfl_down(m, o, 64));
    if (lane == 0) red[wave] = m;
    __syncthreads();
    m = fmaxf(fmaxf(red[0], red[1]), fmaxf(red[2], red[3]));
    __syncthreads();

    float s = 0.f;
    for (int c = t; c < V; c += 256) s += __expf((lr[c] - m) * scale);
#pragma unroll
    for (int o = 32; o > 0; o >>= 1) s += __shfl_down(s, o, 64);
    if (lane == 0) red[wave] = s;
    __syncthreads();
    s = red[0] + red[1] + red[2] + red[3];
    const float inv = 1.f / s;

    for (int c = t; c < V; c += 256)
        pr[c] = __float2bfloat16(__expf((lr[c] - m) * scale) * inv);
    for (int c = V + t; c < W; c += 256)
        pr[c] = __float2bfloat16(0.f);
}

extern "C" void kernel_launch(void* const* d_in, const int* in_sizes, int n_in,
                              void* d_out, int out_size, void* d_ws, size_t ws_size,
                              hipStream_t stream)
{
    const void* inp  = d_in[0];
    const void* x    = d_in[1];
    const void* y    = d_in[2];
    const void* Wq   = d_in[3];
    const void* bq   = d_in[4];
    const void* Wkv  = d_in[5];
    const void* bkv  = d_in[6];
    const void* Wf   = d_in[7];
    const void* bff  = d_in[8];
    const void* Wo   = d_in[9];
    const void* bo   = d_in[10];
    const void* m_k  = d_in[11];
    // d_in[12] = m_v : dead code (v never used by the reference)
    const void* Sm_k = d_in[13];
    const void* Sm_v = d_in[14];

    char* ws = (char*)d_ws;
    int*  flag = (int*)(ws + 0);
    bf16* WqB  = (bf16*)(ws + 256);        // [512][512]
    bf16* WkvB = (bf16*)(ws + 524544);     // [1024][512]
    bf16* WoB  = (bf16*)(ws + 1573120);    // [512][512]
    bf16* WfP  = (bf16*)(ws + 2097408);    // [1152][2080]
    bf16* bqB  = (bf16*)(ws + 6889728);    // [512]
    bf16* bkvB = (bf16*)(ws + 6890752);    // [1024]
    bf16* bfP  = (bf16*)(ws + 6892800);    // [1056] (pad 0)
    bf16* boB  = (bf16*)(ws + 6895104);    // [512]
    bf16* mkS  = (bf16*)(ws + 6896128);    // [8][3][64] = 8*m_k
    bf16* SmkS = (bf16*)(ws + 6899200);    // [8][3][64] = 8*Sm_k
    bf16* SmvS = (bf16*)(ws + 6902272);    // [8][3][64] = sqrt(3)*Sm_v
    bf16* Kb8  = (bf16*)(ws + 6905344);    // [8][2176][64] (rows>=2048 = tokens/0, set once)
    bf16* Skb8 = (bf16*)(ws + 9133568);    // [8][1152][64] (rows>=1024 = tokens/0, set once)
    bf16* SvT8 = (bf16*)(ws + 10313216);   // [8][64][1056] (cols>=1024 = tokens/0, set once)
    bf16* inpBb= (bf16*)(ws + 11394560);   // [1024][512] per-b
    bf16* ctxBb= (bf16*)(ws + 12443136);   // [2048][512] per-b
    bf16* outbb= (bf16*)(ws + 14540288);   // [1024][512] per-b
    bf16* qbh  = (bf16*)(ws + 15588864);   // [1024][64]
    bf16* Svbh = (bf16*)(ws + 15719936);   // [1024][64]
    float* logit=(float*)(ws + 15851008);  // [1024][2176] f32 (reused as [1024][1152])
    bf16* attnc= (bf16*)(ws + 15851008);   // [1024][1056] (overlays logit; logit dead by then)
    bf16* Pc   = (bf16*)(ws + 24763904);   // [1024][2080]
    bf16* Sc   = (bf16*)(ws + 29023744);   // [1024][1056]
    // total: 31,186,432 bytes (~29.8 MB)

    const dim3 blk(256);
    const bf16* nulb = nullptr;
    const float SQRT3 = 1.7320508f;

    detect_dtype<<<dim3(1), dim3(64), 0, stream>>>(inp, flag);

    cvt_gen<<<dim3(1024), blk, 0, stream>>>(Wq,  0, WqB,  262144, 262144, flag, 1.f);
    cvt_gen<<<dim3(2048), blk, 0, stream>>>(Wkv, 0, WkvB, 524288, 524288, flag, 1.f);
    cvt_gen<<<dim3(1024), blk, 0, stream>>>(Wo,  0, WoB,  262144, 262144, flag, 1.f);
    cvt_wf <<<dim3(9360), blk, 0, stream>>>(Wf, WfP, flag);
    cvt_gen<<<dim3(2),    blk, 0, stream>>>(bq,  0, bqB,  512,  512,  flag, 1.f);
    cvt_gen<<<dim3(4),    blk, 0, stream>>>(bkv, 0, bkvB, 1024, 1024, flag, 1.f);
    cvt_gen<<<dim3(5),    blk, 0, stream>>>(bff, 0, bfP,  1027, 1056, flag, 1.f);
    cvt_gen<<<dim3(2),    blk, 0, stream>>>(bo,  0, boB,  512,  512,  flag, 1.f);
    cvt_gen<<<dim3(6),    blk, 0, stream>>>(m_k,  0, mkS,  1536, 1536, flag, 8.f);
    cvt_gen<<<dim3(6),    blk, 0, stream>>>(Sm_k, 0, SmkS, 1536, 1536, flag, 8.f);
    cvt_gen<<<dim3(6),    blk, 0, stream>>>(Sm_v, 0, SmvS, 1536, 1536, flag, SQRT3);
    fill_k_tok  <<<dim3(256), blk, 0, stream>>>(mkS,  Kb8);
    fill_sk_tok <<<dim3(256), blk, 0, stream>>>(SmkS, Skb8);
    fill_svt_tok<<<dim3(64),  blk, 0, stream>>>(SmvS, SvT8);

    for (long b = 0; b < 8; ++b) {
        cvt_gen <<<dim3(2048), blk, 0, stream>>>(inp, b * 524288, inpBb, 524288, 524288, flag, 1.f);
        cvt_ctx_b<<<dim3(4096), blk, 0, stream>>>(x, y, ctxBb, b, flag);

        for (int h = 0; h < 8; ++h) {
            bf16* Kbh  = Kb8  + (long)h * 2176 * 64;
            bf16* Skbh = Skb8 + (long)h * 1152 * 64;
            bf16* SvTh = SvT8 + (long)h * 64 * 1056;
            // qbh = inp_b @ Wq_h^T + bq_h          [1024][64]
            gemm_nt<0><<<dim3(1, 16), blk, 0, stream>>>(inpBb, 512, WqB + (long)h * 64 * 512, 512,
                (void*)qbh, 64, 512, bqB + h * 64, nulb, 0, 64, 64);
            // K rows  = ctx_b @ WkvK_h^T + bkv_h   [2048][64] (token rows persist)
            gemm_nt<0><<<dim3(1, 32), blk, 0, stream>>>(ctxBb, 512, WkvB + (long)h * 64 * 512, 512,
                (void*)Kbh, 64, 512, bkvB + h * 64, nulb, 0, 64, 64);
            // Sk rows = inp_b @ WkvK_h^T + bkv_h   [1024][64]
            gemm_nt<0><<<dim3(1, 16), blk, 0, stream>>>(inpBb, 512, WkvB + (long)h * 64 * 512, 512,
                (void*)Skbh, 64, 512, bkvB + h * 64, nulb, 0, 64, 64);
            // Sv rows = inp_b @ WkvV_h^T + bkv_{512+h}  [1024][64]
            gemm_nt<0><<<dim3(1, 16), blk, 0, stream>>>(inpBb, 512, WkvB + (512L + h * 64) * 512, 512,
                (void*)Svbh, 64, 512, bkvB + 512 + h * 64, nulb, 0, 64, 64);
            transpose_sv<<<dim3(256), blk, 0, stream>>>(Svbh, SvTh);
            // logits = q @ K^T                      [1024][2176] f32
            gemm_nt<1><<<dim3(34, 16), blk, 0, stream>>>(qbh, 64, Kbh, 64,
                (void*)logit, 2176, 64, nulb, nulb, 0, 2176, 2176);
            softmax_rows<<<dim3(1024), blk, 0, stream>>>(logit, 2176, Pc, 2080, 2051, 2080, 0.125f);
            // logits2 = q @ Sk^T                    [1024][1152] f32
            gemm_nt<1><<<dim3(18, 16), blk, 0, stream>>>(qbh, 64, Skbh, 64,
                (void*)logit, 1152, 64, nulb, nulb, 0, 1152, 1152);
            softmax_rows<<<dim3(1024), blk, 0, stream>>>(logit, 1152, Sc, 1056, 1027, 1056, 0.125f);
            // attn = P @ WfP^T + bf + Sc            [1024][1056] bf16
            gemm_nt<0><<<dim3(17, 16), blk, 0, stream>>>(Pc, 2080, WfP, 2080,
                (void*)attnc, 1056, 2080, bfP, Sc, 1056, 1027, 1056);
            // out_h = attn @ SvT^T -> outb_b[:, h*64..]
            gemm_nt<0><<<dim3(1, 16), blk, 0, stream>>>(attnc, 1056, SvTh, 1056,
                (void*)(outbb + h * 64), 512, 1056, nulb, nulb, 0, 64, 64);
        }
        // final_b = outb_b @ Wo^T + bo -> d_out[b]   *** f32 output: d_out is float* ***
        gemm_nt<1><<<dim3(8, 16), blk, 0, stream>>>(outbb, 512, WoB, 512,
            (void*)((float*)d_out + b * 524288), 512, 512, boB, nulb, 0, 512, 512);
    }
}

// Round 6
// 1998.431 us; speedup vs baseline: 14.7060x; 14.7060x over previous
//
#include <hip/hip_runtime.h>
#include <hip/hip_bf16.h>
#include <type_traits>

using bf16 = __hip_bfloat16;
typedef float f32x4 __attribute__((ext_vector_type(4)));
typedef __bf16 bf16x8_t __attribute__((ext_vector_type(8)));
typedef short  s16x8_t  __attribute__((ext_vector_type(8)));

template <typename V, typename = void> struct MfmaWorks : std::false_type {};
template <typename V>
struct MfmaWorks<V, std::void_t<decltype(__builtin_amdgcn_mfma_f32_16x16x32_bf16(
    std::declval<V>(), std::declval<V>(), std::declval<f32x4>(), 0, 0, 0))>> : std::true_type {};
using frag_t = std::conditional_t<MfmaWorks<bf16x8_t>::value, bf16x8_t, s16x8_t>;

template <typename V>
__device__ __forceinline__ f32x4 mfma_16x16x32(V a, V b, f32x4 c) {
    return __builtin_amdgcn_mfma_f32_16x16x32_bf16(a, b, c, 0, 0, 0);
}

__device__ __forceinline__ void gld_lds16(const void* g, void* l) {
    __builtin_amdgcn_global_load_lds(
        (const __attribute__((address_space(1))) unsigned int*)g,
        (__attribute__((address_space(3))) unsigned int*)l, 16, 0, 0);
}

// ---------- runtime-dtype input loader: flag==1 -> f32, flag==0 -> bf16 ----------
__device__ __forceinline__ float ldin(const void* p, long i, int f32) {
    return f32 ? ((const float*)p)[i] : __bfloat162float(((const bf16*)p)[i]);
}

// Probe (proven in r4/r5): even-indexed bf16 reads; real bf16 ~100% sane, f32-low-halves ~8%.
__global__ void detect_dtype(const void* __restrict__ inp, int* __restrict__ flag)
{
    const int t = threadIdx.x;  // 64
    int sane_cnt = 0;
#pragma unroll
    for (int s = 0; s < 4; s++) {
        float v = __bfloat162float(((const bf16*)inp)[2 * (t + 64 * s)]);
        float a = fabsf(v);
        bool sane = (a == 0.f) || (a > 9e-4f && a < 1000.f);
        unsigned long long m = __ballot(sane);
        sane_cnt += (int)__popcll(m);
    }
    if (t == 0) *flag = (sane_cnt > 128) ? 0 : 1;
}

// dst[i] = i<nsrc ? scale*src[srcOff+i] : 0, for i<ndst; 8 elems/thread
__global__ __launch_bounds__(256)
void cvt_gen8(const void* __restrict__ src, long srcOff, bf16* __restrict__ dst,
              long nsrc, long ndst, const int* __restrict__ flag, float scale)
{
    const int f = *flag;
    const long i0 = ((long)blockIdx.x * 256 + threadIdx.x) * 8;
    if (i0 >= ndst) return;
#pragma unroll
    for (int u = 0; u < 8; u++) {
        const long i = i0 + u;
        if (i < ndst) dst[i] = __float2bfloat16(i < nsrc ? scale * ldin(src, srcOff + i, f) : 0.f);
    }
}

// ctx[16384][512] = concat(x[b], y[b]) rows; 8 elems/thread (same row, 512%8==0)
__global__ __launch_bounds__(256)
void cvt_ctx8(const void* __restrict__ x, const void* __restrict__ y,
              bf16* __restrict__ ctx, const int* __restrict__ flag)
{
    const int f = *flag;
    const long i0 = ((long)blockIdx.x * 256 + threadIdx.x) * 8;  // < 8,388,608
    const long r = i0 >> 9, c0 = i0 & 511;
    const long b = r >> 11, jj = r & 2047;
    const void* src = (jj < 1024) ? x : y;
    const long  soff = (jj < 1024) ? ((b * 1024 + jj) * 512 + c0)
                                   : ((b * 1024 + (jj - 1024)) * 512 + c0);
#pragma unroll
    for (int u = 0; u < 8; u++)
        ctx[i0 + u] = __float2bfloat16(ldin(src, soff + u, f));
}

// WfP[1152][2080]: (r<1027 && c<2051) ? Wf[r*2051+c] : 0; 8/thread (2080%8==0)
__global__ __launch_bounds__(256)
void cvt_wf8(const void* __restrict__ Wf, bf16* __restrict__ WfP, const int* __restrict__ flag)
{
    const int f = *flag;
    const long i0 = ((long)blockIdx.x * 256 + threadIdx.x) * 8;  // < 2,396,160
    const long r = i0 / 2080, c0 = i0 % 2080;
#pragma unroll
    for (int u = 0; u < 8; u++) {
        const long c = c0 + u;
        float v = (r < 1027 && c < 2051) ? ldin(Wf, r * 2051 + c, f) : 0.f;
        WfP[i0 + u] = __float2bfloat16(v);
    }
}

// kb[64 bh][2176][64]: j<2048 from Ck; 2048..2050 from mkS (pre-scaled); else 0
__global__ __launch_bounds__(256)
void pack_k(const bf16* __restrict__ Ck, const bf16* __restrict__ mkS, bf16* __restrict__ kb)
{
    const long id = (long)blockIdx.x * 256 + threadIdx.x;   // 1,114,112
    const long bh = id / (2176 * 8);
    const long rem = id % (2176 * 8);
    const long j = rem >> 3;
    const long dg = (rem & 7) << 3;
    const long b = bh >> 3, h = bh & 7;
    bf16* dst = kb + (bh * 2176 + j) * 64 + dg;
    if (j < 2048) {
        *(uint4*)dst = *(const uint4*)(Ck + (b * 2048 + j) * 512 + h * 64 + dg);
    } else if (j < 2051) {
        *(uint4*)dst = *(const uint4*)(mkS + h * 192 + (j - 2048) * 64 + dg);
    } else {
        uint4 zz = {0, 0, 0, 0};
        *(uint4*)dst = zz;
    }
}

// Skb[64 bh][1152][64]: j<1024 from Cskv cols [0,512); 1024..1026 from SmkS; else 0
__global__ __launch_bounds__(256)
void pack_sk(const bf16* __restrict__ Cskv, const bf16* __restrict__ SmkS, bf16* __restrict__ Skb)
{
    const long id = (long)blockIdx.x * 256 + threadIdx.x;   // 589,824
    const long bh = id / (1152 * 8);
    const long rem = id % (1152 * 8);
    const long j = rem >> 3;
    const long dg = (rem & 7) << 3;
    const long b = bh >> 3, h = bh & 7;
    bf16* dst = Skb + (bh * 1152 + j) * 64 + dg;
    if (j < 1024) {
        *(uint4*)dst = *(const uint4*)(Cskv + (b * 1024 + j) * 1024 + h * 64 + dg);
    } else if (j < 1027) {
        *(uint4*)dst = *(const uint4*)(SmkS + h * 192 + (j - 1024) * 64 + dg);
    } else {
        uint4 zz = {0, 0, 0, 0};
        *(uint4*)dst = zz;
    }
}

// SvT[64 bh][128][1056]: SvT[bh][d][j] = Sv[bh][j][d]; d>=64 or j>=1027 -> 0;
// j in [1024,1027) from SmvS (pre-scaled sqrt(3))
__global__ __launch_bounds__(256)
void pack_svt(const bf16* __restrict__ Cskv, const bf16* __restrict__ SmvS, bf16* __restrict__ SvT)
{
    const long id = (long)blockIdx.x * 256 + threadIdx.x;   // 1,081,344
    const long bh = id / (128 * 132);
    const long rem = id % (128 * 132);
    const long dd = rem / 132;
    const long j0 = (rem % 132) << 3;
    const long b = bh >> 3, h = bh & 7;
    __align__(16) bf16 tmp[8];
#pragma unroll
    for (int u = 0; u < 8; u++) {
        const long j = j0 + u;
        float v = 0.f;
        if (dd < 64) {
            if (j < 1024)      v = __bfloat162float(Cskv[(b * 1024 + j) * 1024 + 512 + h * 64 + dd]);
            else if (j < 1027) v = __bfloat162float(SmvS[h * 192 + (j - 1024) * 64 + dd]);
        }
        tmp[u] = __float2bfloat16(v);
    }
    *(uint4*)(SvT + (bh * 128 + dd) * 1056 + j0) = *(const uint4*)tmp;
}

#define TM 128
#define TN 128
#define BK 32

// Batched MFMA NT GEMM (m97 structure): C[z][m][n] = sum_k A[z][m][k]*B[z][n][k] (+bias[n]) (+add[m][n])
// M mult of 128, K mult of 32; B must have grid.x*128 readable rows.
// Stores: n<validN -> val; validN<=n<zeroN -> 0 (bf16) / skipped-bias (f32); n>=zeroN -> skip.
template<int OUTF32>
__global__ __launch_bounds__(256)
void gemm_nt(const bf16* __restrict__ A, long lda, long sAz,
             const bf16* __restrict__ B, long ldb, long sBz,
             void* __restrict__ Cv, long ldc, long sCz,
             int K,
             const bf16* __restrict__ bias,
             const bf16* __restrict__ add, long ldadd,
             int validN, int zeroN)
{
    __shared__ __align__(16) short As[TM * BK];
    __shared__ __align__(16) short Bs[TN * BK];

    const int t = threadIdx.x;
    const int wave = t >> 6;
    const int lane = t & 63;
    const int bn = blockIdx.x, bm = blockIdx.y, z = blockIdx.z;

    const bf16* Ab = A + (long)z * sAz + (long)bm * TM * lda;
    const bf16* Bb = B + (long)z * sBz + (long)bn * TN * ldb;

    const int lrow = t >> 2;          // 0..63
    const int lcol = (t & 3) << 3;    // 0,8,16,24

    const f32x4 vzero = {0.f, 0.f, 0.f, 0.f};
    f32x4 acc[4][4];
#pragma unroll
    for (int i = 0; i < 4; i++)
#pragma unroll
        for (int j = 0; j < 4; j++) acc[i][j] = vzero;

    const int wr = (wave >> 1) << 6;  // 0/64
    const int wc = (wave & 1) << 6;   // 0/64
    const int fr = lane & 15;
    const int fq = (lane >> 4) << 3;

    for (int k0 = 0; k0 < K; k0 += BK) {
        __syncthreads();  // prev iter's ds_reads done before LDS overwrite
        gld_lds16(Ab + (long)lrow * lda + (k0 + lcol),        (char*)As + wave * 1024);
        gld_lds16(Ab + (long)(64 + lrow) * lda + (k0 + lcol), (char*)As + 4096 + wave * 1024);
        gld_lds16(Bb + (long)lrow * ldb + (k0 + lcol),        (char*)Bs + wave * 1024);
        gld_lds16(Bb + (long)(64 + lrow) * ldb + (k0 + lcol), (char*)Bs + 4096 + wave * 1024);
        __builtin_amdgcn_s_waitcnt(0);   // drain vmcnt before barrier
        __syncthreads();

        frag_t af[4], bfr[4];
#pragma unroll
        for (int i = 0; i < 4; i++) af[i]  = *(const frag_t*)&As[(wr + i * 16 + fr) * BK + fq];
#pragma unroll
        for (int j = 0; j < 4; j++) bfr[j] = *(const frag_t*)&Bs[(wc + j * 16 + fr) * BK + fq];
#pragma unroll
        for (int i = 0; i < 4; i++)
#pragma unroll
            for (int j = 0; j < 4; j++)
                acc[i][j] = mfma_16x16x32<frag_t>(af[i], bfr[j], acc[i][j]);
    }

    // epilogue: C/D layout col=lane&15, row=(lane>>4)*4+reg (m89/m91 verified)
    const int r0 = bm * TM + wr + ((lane >> 4) << 2);
    const int c0 = bn * TN + wc + fr;
#pragma unroll
    for (int j = 0; j < 4; j++) {
        const int c = c0 + j * 16;
        if (c >= zeroN) continue;
        const bool valid = c < validN;
        float bv = 0.f;
        if (valid && bias) bv = __bfloat162float(bias[c]);
#pragma unroll
        for (int i = 0; i < 4; i++)
#pragma unroll
            for (int r = 0; r < 4; r++) {
                const long rg = r0 + i * 16 + r;
                if (OUTF32) {
                    ((float*)Cv)[(long)z * sCz + rg * ldc + c] = acc[i][j][r] + bv;
                } else {
                    float v = 0.f;
                    if (valid) {
                        v = acc[i][j][r] + bv;
                        if (add) v += __bfloat162float(add[rg * ldadd + c]);
                    }
                    ((bf16*)Cv)[(long)z * sCz + rg * ldc + c] = __float2bfloat16(v);
                }
            }
    }
}

// row softmax of scale*L over cols [0,V); writes bf16 P, zero-fills cols [V,W)
__global__ __launch_bounds__(256)
void softmax_rows(const float* __restrict__ L, long ldl,
                  bf16* __restrict__ P, long ldp,
                  int V, int W, float scale)
{
    const long row = blockIdx.x;
    const float* lr = L + row * ldl;
    bf16* pr = P + row * ldp;
    const int t = threadIdx.x;
    const int wave = t >> 6, lane = t & 63;
    __shared__ float red[4];

    float m = -3.0e38f;
    for (int c = t; c < V; c += 256) m = fmaxf(m, lr[c]);
#pragma unroll
    for (int o = 32; o > 0; o >>= 1) m = fmaxf(m, __shfl_down(m, o, 64));
    if (lane == 0) red[wave] = m;
    __syncthreads();
    m = fmaxf(fmaxf(red[0], red[1]), fmaxf(red[2], red[3]));
    __syncthreads();

    float s = 0.f;
    for (int c = t; c < V; c += 256) s += __expf((lr[c] - m) * scale);
#pragma unroll
    for (int o = 32; o > 0; o >>= 1) s += __shfl_down(s, o, 64);
    if (lane == 0) red[wave] = s;
    __syncthreads();
    s = red[0] + red[1] + red[2] + red[3];
    const float inv = 1.f / s;

    for (int c = t; c < V; c += 256)
        pr[c] = __float2bfloat16(__expf((lr[c] - m) * scale) * inv);
    for (int c = V + t; c < W; c += 256)
        pr[c] = __float2bfloat16(0.f);
}

extern "C" void kernel_launch(void* const* d_in, const int* in_sizes, int n_in,
                              void* d_out, int out_size, void* d_ws, size_t ws_size,
                              hipStream_t stream)
{
    const void* inp  = d_in[0];
    const void* x    = d_in[1];
    const void* y    = d_in[2];
    const void* Wq   = d_in[3];
    const void* bq   = d_in[4];
    const void* Wkv  = d_in[5];
    const void* bkv  = d_in[6];
    const void* Wf   = d_in[7];
    const void* bff  = d_in[8];
    const void* Wo   = d_in[9];
    const void* bo   = d_in[10];
    const void* m_k  = d_in[11];
    // d_in[12] = m_v : dead code (v never used by the reference)
    const void* Sm_k = d_in[13];
    const void* Sm_v = d_in[14];

    char* ws = (char*)d_ws;
    int*  flag = (int*)(ws + 0);
    bf16* WqB  = (bf16*)(ws + 256);        // [512][512]
    bf16* WkvB = (bf16*)(ws + 524544);     // [1024][512]
    bf16* WoB  = (bf16*)(ws + 1573120);    // [512][512]
    bf16* WfP  = (bf16*)(ws + 2097408);    // [1152][2080]
    bf16* bqB  = (bf16*)(ws + 6889728);    // [512]
    bf16* bkvB = (bf16*)(ws + 6890752);    // [1024]
    bf16* bfP  = (bf16*)(ws + 6892800);    // [1056] (pad 0)
    bf16* boB  = (bf16*)(ws + 6895104);    // [512]
    bf16* mkS  = (bf16*)(ws + 6896128);    // [8][3][64] = 8*m_k
    bf16* SmkS = (bf16*)(ws + 6899200);    // [8][3][64] = 8*Sm_k
    bf16* SmvS = (bf16*)(ws + 6902272);    // [8][3][64] = sqrt(3)*Sm_v
    bf16* qb   = (bf16*)(ws + 6905344);    // [8192][512]
    bf16* kb   = (bf16*)(ws + 15293952);   // [64][2176][64]
    bf16* Skb  = (bf16*)(ws + 33119744);   // [64][1152][64]
    bf16* SvT  = (bf16*)(ws + 42556928);   // [64][128][1056]
    bf16* outb = (bf16*)(ws + 59858432);   // [8192][512]
    char* OV   = ws + 68247040;            // overlay region

    // early overlay (lifetimes: inpB,Cskv die before ctxB is written)
    bf16* inpB = (bf16*)(OV);              // [8192][512]
    bf16* Cskv = (bf16*)(OV + 8388608);    // [8192][1024]
    bf16* ctxB = (bf16*)(OV);              // [16384][512] (reuses inpB+Cskv bytes)
    bf16* Ck   = (bf16*)(OV + 16777216);   // [16384][512]

    // chunk size CH = (b,h) pairs per pass, adaptive to ws_size
    const int CH = (ws_size >= (size_t)208231936) ? 8
                 : (ws_size >= (size_t)138239488) ? 4
                 : (ws_size >= (size_t)103243264) ? 2 : 1;

    // chunk-phase overlay
    float* logit = (float*)(OV);                                    // [CH*1024][2176] f32
    bf16*  Pc    = (bf16*)(OV + (long)CH * 8912896);                // [CH*1024][2080]
    bf16*  Sc    = (bf16*)((char*)Pc + (long)CH * 4259840);         // [CH*1024][1056]
    bf16*  attnc = (bf16*)((char*)Sc + (long)CH * 2162688);         // [CH*1024][1056]

    const dim3 blk(256);
    const bf16* nulb = nullptr;
    const float SQRT3 = 1.7320508f;

    detect_dtype<<<dim3(1), dim3(64), 0, stream>>>(inp, flag);

    // weight/bias/token conversions (f32 or bf16 input -> bf16 ws copies)
    cvt_gen8<<<dim3(128),  blk, 0, stream>>>(Wq,  0, WqB,  262144, 262144, flag, 1.f);
    cvt_gen8<<<dim3(256),  blk, 0, stream>>>(Wkv, 0, WkvB, 524288, 524288, flag, 1.f);
    cvt_gen8<<<dim3(128),  blk, 0, stream>>>(Wo,  0, WoB,  262144, 262144, flag, 1.f);
    cvt_wf8 <<<dim3(1170), blk, 0, stream>>>(Wf, WfP, flag);
    cvt_gen8<<<dim3(1),    blk, 0, stream>>>(bq,  0, bqB,  512,  512,  flag, 1.f);
    cvt_gen8<<<dim3(1),    blk, 0, stream>>>(bkv, 0, bkvB, 1024, 1024, flag, 1.f);
    cvt_gen8<<<dim3(1),    blk, 0, stream>>>(bff, 0, bfP,  1027, 1056, flag, 1.f);
    cvt_gen8<<<dim3(1),    blk, 0, stream>>>(bo,  0, boB,  512,  512,  flag, 1.f);
    cvt_gen8<<<dim3(1),    blk, 0, stream>>>(m_k,  0, mkS,  1536, 1536, flag, 8.f);
    cvt_gen8<<<dim3(1),    blk, 0, stream>>>(Sm_k, 0, SmkS, 1536, 1536, flag, 8.f);
    cvt_gen8<<<dim3(1),    blk, 0, stream>>>(Sm_v, 0, SmvS, 1536, 1536, flag, SQRT3);

    // early phase
    cvt_gen8<<<dim3(2048), blk, 0, stream>>>(inp, 0, inpB, 4194304, 4194304, flag, 1.f);
    // q = inpB @ Wq^T + bq    [8192,512]
    gemm_nt<0><<<dim3(4, 64, 1), blk, 0, stream>>>(inpB, 512, 0, WqB, 512, 0, (void*)qb, 512, 0,
                                                   512, bqB, nulb, 0, 512, 512);
    // Cskv = inpB @ Wkv^T + bkv   [8192,1024]
    gemm_nt<0><<<dim3(8, 64, 1), blk, 0, stream>>>(inpB, 512, 0, WkvB, 512, 0, (void*)Cskv, 1024, 0,
                                                   512, bkvB, nulb, 0, 1024, 1024);
    pack_sk <<<dim3(2304), blk, 0, stream>>>(Cskv, SmkS, Skb);
    pack_svt<<<dim3(4224), blk, 0, stream>>>(Cskv, SmvS, SvT);
    // inpB, Cskv dead; ctxB reuses their bytes
    cvt_ctx8<<<dim3(4096), blk, 0, stream>>>(x, y, ctxB, flag);
    // Ck = ctxB @ Wkv[:512]^T + bkv[:512]   [16384,512]
    gemm_nt<0><<<dim3(4, 128, 1), blk, 0, stream>>>(ctxB, 512, 0, WkvB, 512, 0, (void*)Ck, 512, 0,
                                                    512, bkvB, nulb, 0, 512, 512);
    pack_k<<<dim3(4352), blk, 0, stream>>>(Ck, mkS, kb);
    // ctxB/Ck dead; chunk buffers reuse the overlay

    const int passes = 64 / CH;
    for (int p = 0; p < passes; ++p) {
        const long bh0 = (long)p * CH;
        const long b = bh0 >> 3, h0 = bh0 & 7;
        const bf16* qc = qb + b * 1024 * 512 + h0 * 64;
        // logits = q_bh @ k_bh^T   [CH][1024][2176] f32 (cols>=2051 are exact zeros, unread)
        gemm_nt<1><<<dim3(17, 8, CH), blk, 0, stream>>>(qc, 512, 64,
            kb + bh0 * 2176 * 64, 64, 2176L * 64,
            (void*)logit, 2176, 1024L * 2176, 64, nulb, nulb, 0, 2176, 2176);
        softmax_rows<<<dim3(CH * 1024), blk, 0, stream>>>(logit, 2176, Pc, 2080, 2051, 2080, 0.125f);
        // logits2 = q_bh @ Sk_bh^T  [CH][1024][1152] f32
        gemm_nt<1><<<dim3(9, 8, CH), blk, 0, stream>>>(qc, 512, 64,
            Skb + bh0 * 1152 * 64, 64, 1152L * 64,
            (void*)logit, 1152, 1024L * 1152, 64, nulb, nulb, 0, 1152, 1152);
        softmax_rows<<<dim3(CH * 1024), blk, 0, stream>>>(logit, 1152, Sc, 1056, 1027, 1056, 0.125f);
        // attn = P @ WfP^T + bf + Sc   [CH*1024][1056] bf16 (cols 1027..1055 zeroed)
        gemm_nt<0><<<dim3(9, CH * 8, 1), blk, 0, stream>>>(Pc, 2080, 0, WfP, 2080, 0,
            (void*)attnc, 1056, 0, 2080, bfP, Sc, 1056, 1027, 1056);
        // out_bh = attn_bh @ SvT_bh^T -> outb[b][i][(h0+z)*64+d]
        gemm_nt<0><<<dim3(1, 8, CH), blk, 0, stream>>>(attnc, 1056, 1024L * 1056,
            SvT + bh0 * 128 * 1056, 1056, 128L * 1056,
            (void*)(outb + b * 1024 * 512 + h0 * 64), 512, 64, 1056, nulb, nulb, 0, 64, 64);
    }
    // final = outb @ Wo^T + bo -> d_out (f32)
    gemm_nt<1><<<dim3(4, 64, 1), blk, 0, stream>>>(outb, 512, 0, WoB, 512, 0, d_out, 512, 0,
                                                   512, boB, nulb, 0, 512, 512);
}